// Round 1
// baseline (212.997 us; speedup 1.0000x reference)
//
#include <hip/hip_runtime.h>

// Projector: out[n,p,o] = x@Wd^T + bd + softmax_l((x@W1^T)·(t@W2^T)^T) @ (t@W3^T + b3)
// N=16, HW=3136, L=64, C_IN=256, C_OUT=512, D=256. fp32 in/out.
// R5: occupancy attack. Diagnosis: unified VGPR+AGPR ~160/wave -> 3 waves/SIMD
// -> only ONE 8-wave block resident per CU -> barrier chain fully serial
// (MfmaUtil 12%, VALU 8.5%, HBM 27%: latency-bound).
//  - M-tile 64->32, block 512->256 thr, grid 784->1568.
//  - GEMM4/GEMM3/epilogue o-split in time: acc[2][4]=32 regs (was 64).
//  - LDS 52.2KB -> 34.8KB (xs 32x264 + xq double-buffer + 512B partials)
//    => 4 blocks/CU (16 waves) vs 1 block (8 waves).
//  - every wave does GEMM2+softmax (split by row-block x l-half, online
//    two-partial combine via LDS) -- no idle waves.
//  - xq double-buffer removes one barrier (5 total).
//  - epilogue: direct scalar stores (L2 write-combines 64B segments into
//    full lines); frees xs for GEMM4-oh1, no LDS transpose.

typedef unsigned short u16;
using half8 = __attribute__((ext_vector_type(8))) _Float16;
using f32x4 = __attribute__((ext_vector_type(4))) float;

__device__ __forceinline__ u16 f2h(float f) {
  _Float16 h = (_Float16)f;            // RNE
  union { _Float16 h; u16 u; } cv; cv.h = h;
  return cv.u;
}

__device__ __forceinline__ f32x4 mfma16(half8 a, half8 b, f32x4 c) {
  return __builtin_amdgcn_mfma_f32_16x16x32_f16(a, b, c, 0, 0, 0);
}

// ---------------------------------------------------------------------------
// K0: fp32 -> f16 + reblock into fragment-linear layout (KC=8 k-chunks).
// flat = ((row/16)*8 + k/32)*512 + ((k/8)%4)*128 + (row%16)*8 + (k%8)
// ---------------------------------------------------------------------------
__global__ __launch_bounds__(256) void reblock_kernel(
    const float* __restrict__ W1, const float* __restrict__ W2,
    const float* __restrict__ W3, const float* __restrict__ Wd,
    const float* __restrict__ t,
    u16* __restrict__ W1f, u16* __restrict__ W2f, u16* __restrict__ W3f,
    u16* __restrict__ Wdf, u16* __restrict__ tf) {
  int b = blockIdx.x, k = threadIdx.x;
  const float* src; u16* dst; int row;
  if (b < 256)       { src = W1; dst = W1f; row = b; }
  else if (b < 512)  { src = W2; dst = W2f; row = b - 256; }
  else if (b < 1024) { src = W3; dst = W3f; row = b - 512; }
  else if (b < 1536) { src = Wd; dst = Wdf; row = b - 1024; }
  else               { src = t;  dst = tf;  row = b - 1536; }
  float v = src[(size_t)row*256 + k];
  int flat = ((row >> 4)*8 + (k >> 5))*512 + ((k >> 3) & 3)*128 + (row & 15)*8 + (k & 7);
  dst[flat] = f2h(v);
}

// ---------------------------------------------------------------------------
// K1: merged t_q and t3 kernels, all operands FL, outputs written FL.
// blocks 0..63:   tq[n,l,e] = t@W2^T        -> tqf (rows=l per n, K=e=256)
// blocks 64..191: t3[n,o,l] = t@W3^T + b3   -> t3f (rows=o per n, K=l=64)
// ---------------------------------------------------------------------------
__global__ __launch_bounds__(256) void tq_t3t_kernel(
    const u16* __restrict__ tf, const u16* __restrict__ W2f,
    const u16* __restrict__ W3f, const float* __restrict__ b3,
    u16* __restrict__ tqf, u16* __restrict__ t3f) {
  const int tid = threadIdx.x, w = tid >> 6, lane = tid & 63;
  const int quad = lane >> 4, l16 = lane & 15;
  const int b = blockIdx.x;

  if (b < 64) {
    const int n = b >> 2, eb = b & 3;
    const int gW2 = eb*4 + w;          // e-row group (e0 = eb*64 + w*16)
    f32x4 acc[4];
    #pragma unroll
    for (int mt = 0; mt < 4; ++mt) acc[mt] = (f32x4){0.f, 0.f, 0.f, 0.f};
    #pragma unroll
    for (int kc = 0; kc < 8; ++kc) {
      half8 bf = *(const half8*)(W2f + (gW2*8 + kc)*512 + lane*8);
      #pragma unroll
      for (int mt = 0; mt < 4; ++mt) {
        half8 a = *(const half8*)(tf + ((n*4 + mt)*8 + kc)*512 + lane*8);
        acc[mt] = mfma16(a, bf, acc[mt]);
      }
    }
    // value at (l = mt*16+quad*4+r, e = eb*64+w*16+l16); write FL for GEMM2
    #pragma unroll
    for (int mt = 0; mt < 4; ++mt)
      #pragma unroll
      for (int r = 0; r < 4; ++r) {
        int flat = ((n*4 + mt)*8 + eb*2 + (w >> 1))*512
                 + ((w & 1)*2 + (l16 >> 3))*128 + (quad*4 + r)*8 + (l16 & 7);
        tqf[flat] = f2h(acc[mt][r]);
      }
  } else {
    const int b2 = b - 64;
    const int n = b2 >> 3, ob = b2 & 7;
    const int gW3 = ob*4 + w;          // o-row group (o0 = ob*64 + w*16)
    f32x4 acc[4];
    #pragma unroll
    for (int nt = 0; nt < 4; ++nt) acc[nt] = (f32x4){0.f, 0.f, 0.f, 0.f};
    #pragma unroll
    for (int kc = 0; kc < 8; ++kc) {
      half8 a = *(const half8*)(W3f + (gW3*8 + kc)*512 + lane*8);
      #pragma unroll
      for (int nt = 0; nt < 4; ++nt) {
        half8 bf = *(const half8*)(tf + ((n*4 + nt)*8 + kc)*512 + lane*8);
        acc[nt] = mfma16(a, bf, acc[nt]);
      }
    }
    // value at (o = ob*64+w*16+quad*4+r, l = nt*16+l16); write FL for GEMM3
    #pragma unroll
    for (int nt = 0; nt < 4; ++nt)
      #pragma unroll
      for (int r = 0; r < 4; ++r) {
        int o = ob*64 + w*16 + quad*4 + r;
        int flat = ((n*32 + ob*4 + w)*2 + (nt >> 1))*512
                 + ((nt & 1)*2 + (l16 >> 3))*128 + (quad*4 + r)*8 + (l16 & 7);
        t3f[flat] = f2h(acc[nt][r] + b3[o]);
      }
  }
}

// ---------------------------------------------------------------------------
// K2: main fused kernel. grid 1568 = 16 n * 98 row-tiles of 32; 256 threads.
// smem carve (34,816 B):
//   [0, 16896):        xs  32 x 264 u16
//   [16896, 25600):    xq0 32 x 136 u16 (xq h0; later aw 32 x 72)
//   [25600, 34304):    xq1 32 x 136 u16 (xq h1)
//   [34304, 34816):    parts: 64 x {mx, ps} f32 (softmax partials)
// 5 barriers per block. 4 blocks/CU by LDS (139,264 B) and regs (<=128).
// ---------------------------------------------------------------------------
__global__ __launch_bounds__(256, 4) void main_kernel(
    const float* __restrict__ x, const u16* __restrict__ W1f,
    const u16* __restrict__ Wdf, const u16* __restrict__ tqf,
    const u16* __restrict__ t3f, const float* __restrict__ bd,
    float* __restrict__ out) {
  __shared__ __attribute__((aligned(16))) char smem[34816];
  u16* xs  = (u16*)smem;                     // 32 x 264
  u16* xq0 = (u16*)(smem + 16896);           // 32 x 136 (later aw 32 x 72)
  u16* xq1 = (u16*)(smem + 25600);           // 32 x 136
  float* parts = (float*)(smem + 34304);     // 64 x float2 {mx, ps}

  const int bid = blockIdx.x;
  const int n  = bid / 98;
  const int pt = bid - n*98;
  const int m0 = pt * 32;
  const int tid = threadIdx.x, w = tid >> 6, lane = tid & 63;
  const int quad = lane >> 4, l16 = lane & 15;
  const int rb = w & 1;        // GEMM2 row-block (rows rb*16..rb*16+15)
  const int lh = w >> 1;       // GEMM2 l-half (cols lh*32..lh*32+31)

  // ---- prefetch W1f h0 group (e-group w*2) + bias ----
  half8 w1a[8];
  {
    const u16* p = W1f + (size_t)(w*2)*8*512;
    #pragma unroll
    for (int kc = 0; kc < 8; ++kc) w1a[kc] = *(const half8*)(p + kc*512 + lane*8);
  }
  float bias[8];
  #pragma unroll
  for (int og = 0; og < 8; ++og) bias[og] = bd[w*128 + og*16 + l16];

  // ---- stage x tile: 32x256 fp32 -> f16 LDS (coalesced float4) ----
  {
    const float4* xg = (const float4*)(x + (size_t)(n*3136 + m0)*256);
    #pragma unroll
    for (int it = 0; it < 8; ++it) {
      int idx = it*256 + tid;
      int r = idx >> 6, c4 = idx & 63;
      float4 v = xg[idx];
      ushort4 u;
      u.x = f2h(v.x); u.y = f2h(v.y); u.z = f2h(v.z); u.w = f2h(v.w);
      *(ushort4*)(&xs[r*264 + c4*4]) = u;
    }
  }
  __syncthreads();                                             // B1

  // ---- P1: GEMM1 h0 (e-groups w*2, w*2+1), write xq0 ----
  f32x4 acc1[2][2];
  #pragma unroll
  for (int i = 0; i < 2; ++i)
    #pragma unroll
    for (int mt = 0; mt < 2; ++mt) acc1[i][mt] = (f32x4){0.f, 0.f, 0.f, 0.f};
  {
    const u16* p1 = W1f + (size_t)(w*2 + 1)*8*512;
    #pragma unroll
    for (int kc = 0; kc < 8; ++kc) {
      half8 a0 = *(const half8*)(&xs[(l16)*264 + kc*32 + quad*8]);
      half8 a1 = *(const half8*)(&xs[(16 + l16)*264 + kc*32 + quad*8]);
      acc1[0][0] = mfma16(a0, w1a[kc], acc1[0][0]);
      acc1[0][1] = mfma16(a1, w1a[kc], acc1[0][1]);
      half8 bf = *(const half8*)(p1 + kc*512 + lane*8);
      acc1[1][0] = mfma16(a0, bf, acc1[1][0]);
      acc1[1][1] = mfma16(a1, bf, acc1[1][1]);
    }
  }
  // value at (row = mt*16+quad*4+r, e = (w*2+i)*16 + l16)
  #pragma unroll
  for (int i = 0; i < 2; ++i)
    #pragma unroll
    for (int mt = 0; mt < 2; ++mt)
      #pragma unroll
      for (int r = 0; r < 4; ++r)
        xq0[(mt*16 + quad*4 + r)*136 + (w*2 + i)*16 + l16] = f2h(acc1[i][mt][r]);
  __syncthreads();                                             // B2

  // ---- P2: GEMM2 h0 (all waves) + GEMM1 h1 -> xq1 (own buffer, no pre-barrier)
  f32x4 acc2[2];
  acc2[0] = (f32x4){0.f, 0.f, 0.f, 0.f};
  acc2[1] = (f32x4){0.f, 0.f, 0.f, 0.f};
  #pragma unroll
  for (int k2 = 0; k2 < 4; ++k2) {
    half8 a = *(const half8*)(&xq0[(rb*16 + l16)*136 + k2*32 + quad*8]);
    #pragma unroll
    for (int j = 0; j < 2; ++j) {
      half8 bf = *(const half8*)(tqf + ((size_t)(n*4 + lh*2 + j)*8 + k2)*512 + lane*8);
      acc2[j] = mfma16(a, bf, acc2[j]);
    }
  }
  {
    f32x4 acc1b[2][2];
    #pragma unroll
    for (int i = 0; i < 2; ++i)
      #pragma unroll
      for (int mt = 0; mt < 2; ++mt) acc1b[i][mt] = (f32x4){0.f, 0.f, 0.f, 0.f};
    const u16* pa = W1f + (size_t)(8 + w*2)*8*512;
    const u16* pb = W1f + (size_t)(9 + w*2)*8*512;
    #pragma unroll
    for (int kc = 0; kc < 8; ++kc) {
      half8 a0 = *(const half8*)(&xs[(l16)*264 + kc*32 + quad*8]);
      half8 a1 = *(const half8*)(&xs[(16 + l16)*264 + kc*32 + quad*8]);
      half8 bfA = *(const half8*)(pa + kc*512 + lane*8);
      half8 bfB = *(const half8*)(pb + kc*512 + lane*8);
      acc1b[0][0] = mfma16(a0, bfA, acc1b[0][0]);
      acc1b[0][1] = mfma16(a1, bfA, acc1b[0][1]);
      acc1b[1][0] = mfma16(a0, bfB, acc1b[1][0]);
      acc1b[1][1] = mfma16(a1, bfB, acc1b[1][1]);
    }
    #pragma unroll
    for (int i = 0; i < 2; ++i)
      #pragma unroll
      for (int mt = 0; mt < 2; ++mt)
        #pragma unroll
        for (int r = 0; r < 4; ++r)
          xq1[(mt*16 + quad*4 + r)*136 + (w*2 + i)*16 + l16] = f2h(acc1b[i][mt][r]);
  }
  __syncthreads();   // B3: xq1 ready; xq0 (buf0) reads done -> aw may alias later

  // ---- P3: GEMM2 h1 + GEMM4 oh0 + softmax partials ----
  #pragma unroll
  for (int k2 = 0; k2 < 4; ++k2) {
    half8 a = *(const half8*)(&xq1[(rb*16 + l16)*136 + k2*32 + quad*8]);
    #pragma unroll
    for (int j = 0; j < 2; ++j) {
      half8 bf = *(const half8*)(tqf + ((size_t)(n*4 + lh*2 + j)*8 + 4 + k2)*512 + lane*8);
      acc2[j] = mfma16(a, bf, acc2[j]);
    }
  }
  f32x4 acc[2][4];
  #pragma unroll
  for (int mt = 0; mt < 2; ++mt)
    #pragma unroll
    for (int ot = 0; ot < 4; ++ot) acc[mt][ot] = (f32x4){0.f, 0.f, 0.f, 0.f};
  #pragma unroll
  for (int kc = 0; kc < 8; ++kc) {
    half8 a0 = *(const half8*)(&xs[(l16)*264 + kc*32 + quad*8]);
    half8 a1 = *(const half8*)(&xs[(16 + l16)*264 + kc*32 + quad*8]);
    #pragma unroll
    for (int ot = 0; ot < 4; ++ot) {
      half8 bf = *(const half8*)(Wdf + ((size_t)(w*8 + ot)*8 + kc)*512 + lane*8);
      acc[0][ot] = mfma16(a0, bf, acc[0][ot]);
      acc[1][ot] = mfma16(a1, bf, acc[1][ot]);
    }
  }
  // per-wave softmax partials over this wave's 32 l-cols (2 lt x 16 lanes)
  float mx_[4], ps_[4], e0_[4], e1_[4];
  #pragma unroll
  for (int r = 0; r < 4; ++r) {
    float s0 = acc2[0][r], s1 = acc2[1][r];
    float mx = fmaxf(s0, s1);
    #pragma unroll
    for (int off = 8; off >= 1; off >>= 1) mx = fmaxf(mx, __shfl_xor(mx, off, 64));
    float e0 = __expf(s0 - mx), e1 = __expf(s1 - mx);
    float ps = e0 + e1;
    #pragma unroll
    for (int off = 8; off >= 1; off >>= 1) ps += __shfl_xor(ps, off, 64);
    mx_[r] = mx; ps_[r] = ps; e0_[r] = e0; e1_[r] = e1;
    if (l16 == 0) {
      int pi = (rb*2 + lh)*16 + quad*4 + r;
      parts[pi*2]     = mx;
      parts[pi*2 + 1] = ps;
    }
  }
  __syncthreads();                                             // B4

  // ---- combine partials (online-softmax merge), write aw into buf0 ----
  u16* aw = xq0;
  #pragma unroll
  for (int r = 0; r < 4; ++r) {
    int pi = (rb*2 + (1 - lh))*16 + quad*4 + r;
    float mxo = parts[pi*2], pso = parts[pi*2 + 1];
    float g  = fmaxf(mx_[r], mxo);
    float sA = __expf(mx_[r] - g), sB = __expf(mxo - g);
    float inv = 1.0f / (ps_[r]*sA + pso*sB);
    float scl = sA * inv;
    int row = (rb*16 + quad*4 + r)*72;
    aw[row + lh*32 + l16]      = f2h(e0_[r]*scl);
    aw[row + lh*32 + 16 + l16] = f2h(e1_[r]*scl);
  }
  __syncthreads();                                             // B5

  // ---- P4: GEMM3 oh0 -> epi oh0 -> GEMM4 oh1 -> GEMM3 oh1 -> epi oh1 ----
  #pragma unroll
  for (int kc3 = 0; kc3 < 2; ++kc3) {
    half8 a0 = *(const half8*)(&aw[(l16)*72 + kc3*32 + quad*8]);
    half8 a1 = *(const half8*)(&aw[(16 + l16)*72 + kc3*32 + quad*8]);
    #pragma unroll
    for (int ot = 0; ot < 4; ++ot) {
      half8 bf = *(const half8*)(t3f + ((size_t)(n*32 + w*8 + ot)*2 + kc3)*512 + lane*8);
      acc[0][ot] = mfma16(a0, bf, acc[0][ot]);
      acc[1][ot] = mfma16(a1, bf, acc[1][ot]);
    }
  }
  float* ob = out + (size_t)(n*3136 + m0)*512 + w*128;
  #pragma unroll
  for (int mt = 0; mt < 2; ++mt)
    #pragma unroll
    for (int ot = 0; ot < 4; ++ot)
      #pragma unroll
      for (int r = 0; r < 4; ++r)
        ob[(size_t)(mt*16 + quad*4 + r)*512 + ot*16 + l16] = acc[mt][ot][r] + bias[ot];

  // oh1 (reuse acc; xs and aw untouched since their barriers)
  #pragma unroll
  for (int mt = 0; mt < 2; ++mt)
    #pragma unroll
    for (int ot = 0; ot < 4; ++ot) acc[mt][ot] = (f32x4){0.f, 0.f, 0.f, 0.f};
  #pragma unroll
  for (int kc = 0; kc < 8; ++kc) {
    half8 a0 = *(const half8*)(&xs[(l16)*264 + kc*32 + quad*8]);
    half8 a1 = *(const half8*)(&xs[(16 + l16)*264 + kc*32 + quad*8]);
    #pragma unroll
    for (int ot = 0; ot < 4; ++ot) {
      half8 bf = *(const half8*)(Wdf + ((size_t)(w*8 + 4 + ot)*8 + kc)*512 + lane*8);
      acc[0][ot] = mfma16(a0, bf, acc[0][ot]);
      acc[1][ot] = mfma16(a1, bf, acc[1][ot]);
    }
  }
  #pragma unroll
  for (int kc3 = 0; kc3 < 2; ++kc3) {
    half8 a0 = *(const half8*)(&aw[(l16)*72 + kc3*32 + quad*8]);
    half8 a1 = *(const half8*)(&aw[(16 + l16)*72 + kc3*32 + quad*8]);
    #pragma unroll
    for (int ot = 0; ot < 4; ++ot) {
      half8 bf = *(const half8*)(t3f + ((size_t)(n*32 + w*8 + 4 + ot)*2 + kc3)*512 + lane*8);
      acc[0][ot] = mfma16(a0, bf, acc[0][ot]);
      acc[1][ot] = mfma16(a1, bf, acc[1][ot]);
    }
  }
  #pragma unroll
  for (int mt = 0; mt < 2; ++mt)
    #pragma unroll
    for (int ot = 0; ot < 4; ++ot)
      #pragma unroll
      for (int r = 0; r < 4; ++r)
        ob[(size_t)(mt*16 + quad*4 + r)*512 + 64 + ot*16 + l16] = acc[mt][ot][r] + bias[4 + ot];
}

// ---------------------------------------------------------------------------
extern "C" void kernel_launch(void* const* d_in, const int* in_sizes, int n_in,
                              void* d_out, int out_size, void* d_ws, size_t ws_size,
                              hipStream_t stream) {
  const float* x  = (const float*)d_in[0];
  const float* t  = (const float*)d_in[1];
  const float* W1 = (const float*)d_in[2];
  const float* W2 = (const float*)d_in[3];
  const float* W3 = (const float*)d_in[4];
  const float* b3 = (const float*)d_in[5];
  const float* Wd = (const float*)d_in[6];
  const float* bd = (const float*)d_in[7];
  float* out = (float*)d_out;

  // workspace layout (bytes), ~2.9 MB total — all fragment-linear f16
  char* ws = (char*)d_ws;
  u16* W1f = (u16*)(ws + 0);        //  131072
  u16* W2f = (u16*)(ws + 131072);   //  131072
  u16* W3f = (u16*)(ws + 262144);   //  262144
  u16* Wdf = (u16*)(ws + 524288);   //  262144
  u16* tf  = (u16*)(ws + 786432);   //  524288
  u16* tqf = (u16*)(ws + 1310720);  //  524288
  u16* t3f = (u16*)(ws + 1835008);  //  1048576  (end 2883584)

  hipLaunchKernelGGL(reblock_kernel, dim3(2560), dim3(256), 0, stream,
                     W1, W2, W3, Wd, t, W1f, W2f, W3f, Wdf, tf);
  hipLaunchKernelGGL(tq_t3t_kernel, dim3(192), dim3(256), 0, stream,
                     tf, W2f, W3f, b3, tqf, t3f);
  hipLaunchKernelGGL(main_kernel, dim3(1568), dim3(256), 0, stream,
                     x, W1f, Wdf, tqf, t3f, bd, out);
}

// Round 2
// 205.688 us; speedup vs baseline: 1.0355x; 1.0355x over previous
//
#include <hip/hip_runtime.h>

// Projector: out[n,p,o] = x@Wd^T + bd + softmax_l((x@W1^T)·(t@W2^T)^T) @ (t@W3^T + b3)
// N=16, HW=3136, L=64, C_IN=256, C_OUT=512, D=256. fp32 in/out.
// R6: algebraic refactor. softmax arg = x @ (W1^T W2) @ t^T, so precompute
//   G = W1^T W2 (256x256, f32 accum, n-independent) and Mt[n] = t[n]@G-ish
//   (same GEMM shape as old tq). Main kernel loses GEMM1 (-27% MFMA work),
//   the xq LDS round-trip, W1f loads, and 2 of 6 barriers.
// Main kernel: 784 blocks x 512 thr, 64-row tiles, 4 barriers:
//   stage xs -> B1 -> GEMM2 (all 8 waves, 2 tiles each) -> partials -> B2
//   -> merge+aw -> B3 -> GEMM4+GEMM3 (shared acc) -> B4 -> transpose epilogue.
// LDS 44,032 B (xs 64x264 + aw 64x72 + parts 1KB) => 2 blocks/CU resident.

typedef unsigned short u16;
using half8 = __attribute__((ext_vector_type(8))) _Float16;
using f32x4 = __attribute__((ext_vector_type(4))) float;

__device__ __forceinline__ u16 f2h(float f) {
  _Float16 h = (_Float16)f;            // RNE
  union { _Float16 h; u16 u; } cv; cv.h = h;
  return cv.u;
}

__device__ __forceinline__ f32x4 mfma16(half8 a, half8 b, f32x4 c) {
  return __builtin_amdgcn_mfma_f32_16x16x32_f16(a, b, c, 0, 0, 0);
}

// ---------------------------------------------------------------------------
// K0: reblock W3/Wd/t to fragment-linear f16, and compute Gt = (W1^T W2)^T
// in f32 (Gt[c,e] = sum_d W1[d,c]*W2[d,e]), rounded once to f16 FL.
// FL: flat(row,k) = ((row/16)*8 + k/32)*512 + ((k/8)%4)*128 + (row%16)*8 + (k%8)
// ---------------------------------------------------------------------------
__global__ __launch_bounds__(256) void prep_kernel(
    const float* __restrict__ W1, const float* __restrict__ W2,
    const float* __restrict__ W3, const float* __restrict__ Wd,
    const float* __restrict__ t,
    u16* __restrict__ W3f, u16* __restrict__ Wdf, u16* __restrict__ tf,
    u16* __restrict__ Gtf) {
  int b = blockIdx.x, k = threadIdx.x;
  if (b < 2048) {
    const float* src; u16* dst; int row;
    if (b < 512)       { src = W3; dst = W3f; row = b; }
    else if (b < 1024) { src = Wd; dst = Wdf; row = b - 512; }
    else               { src = t;  dst = tf;  row = b - 1024; }
    float v = src[(size_t)row*256 + k];
    int flat = ((row >> 4)*8 + (k >> 5))*512 + ((k >> 3) & 3)*128 + (row & 15)*8 + (k & 7);
    dst[flat] = f2h(v);
  } else {
    // Gt row c = b-2048 (uniform per block); thread k = e (coalesced W2 reads)
    int c = b - 2048;
    float g = 0.f;
    #pragma unroll 8
    for (int d = 0; d < 256; ++d)
      g = fmaf(W1[d*256 + c], W2[d*256 + k], g);
    int flat = ((c >> 4)*8 + (k >> 5))*512 + ((k >> 3) & 3)*128 + (c & 15)*8 + (k & 7);
    Gtf[flat] = f2h(g);
  }
}

// ---------------------------------------------------------------------------
// K1: per-n small GEMMs, all operands FL, outputs written FL.
// blocks 0..63:   Mt[n,l,c] = sum_e t[n,l,e]*Gt[c,e]  -> mtf (rows=l, K=c=256)
// blocks 64..191: t3[n,o,l] = t@W3^T + b3             -> t3f (rows=o, K=l=64)
// ---------------------------------------------------------------------------
__global__ __launch_bounds__(256) void mt_t3_kernel(
    const u16* __restrict__ tf, const u16* __restrict__ Gtf,
    const u16* __restrict__ W3f, const float* __restrict__ b3,
    u16* __restrict__ mtf, u16* __restrict__ t3f) {
  const int tid = threadIdx.x, w = tid >> 6, lane = tid & 63;
  const int quad = lane >> 4, l16 = lane & 15;
  const int b = blockIdx.x;

  if (b < 64) {
    const int n = b >> 2, eb = b & 3;      // eb = c-quarter
    const int gc = eb*4 + w;               // c-row group (c0 = eb*64 + w*16)
    f32x4 acc[4];
    #pragma unroll
    for (int mt = 0; mt < 4; ++mt) acc[mt] = (f32x4){0.f, 0.f, 0.f, 0.f};
    #pragma unroll
    for (int kc = 0; kc < 8; ++kc) {
      half8 bf = *(const half8*)(Gtf + (gc*8 + kc)*512 + lane*8);
      #pragma unroll
      for (int mt = 0; mt < 4; ++mt) {
        half8 a = *(const half8*)(tf + ((n*4 + mt)*8 + kc)*512 + lane*8);
        acc[mt] = mfma16(a, bf, acc[mt]);
      }
    }
    // value at (l = mt*16+quad*4+r, c = eb*64+w*16+l16); write FL for GEMM2
    #pragma unroll
    for (int mt = 0; mt < 4; ++mt)
      #pragma unroll
      for (int r = 0; r < 4; ++r) {
        int flat = ((n*4 + mt)*8 + eb*2 + (w >> 1))*512
                 + ((w & 1)*2 + (l16 >> 3))*128 + (quad*4 + r)*8 + (l16 & 7);
        mtf[flat] = f2h(acc[mt][r]);
      }
  } else {
    const int b2 = b - 64;
    const int n = b2 >> 3, ob = b2 & 7;
    const int gW3 = ob*4 + w;          // o-row group (o0 = ob*64 + w*16)
    f32x4 acc[4];
    #pragma unroll
    for (int nt = 0; nt < 4; ++nt) acc[nt] = (f32x4){0.f, 0.f, 0.f, 0.f};
    #pragma unroll
    for (int kc = 0; kc < 8; ++kc) {
      half8 a = *(const half8*)(W3f + (gW3*8 + kc)*512 + lane*8);
      #pragma unroll
      for (int nt = 0; nt < 4; ++nt) {
        half8 bf = *(const half8*)(tf + ((n*4 + nt)*8 + kc)*512 + lane*8);
        acc[nt] = mfma16(a, bf, acc[nt]);
      }
    }
    // value at (o = ob*64+w*16+quad*4+r, l = nt*16+l16); write FL for GEMM3
    #pragma unroll
    for (int nt = 0; nt < 4; ++nt)
      #pragma unroll
      for (int r = 0; r < 4; ++r) {
        int o = ob*64 + w*16 + quad*4 + r;
        int flat = ((n*32 + ob*4 + w)*2 + (nt >> 1))*512
                 + ((nt & 1)*2 + (l16 >> 3))*128 + (quad*4 + r)*8 + (l16 & 7);
        t3f[flat] = f2h(acc[nt][r] + b3[o]);
      }
  }
}

// ---------------------------------------------------------------------------
// K2: main fused kernel. grid 784 = 16 n * 49 row-tiles of 64; 512 threads.
// smem carve (44,032 B):
//   [0, 33792):       xs 64 x 264 u16 (later per-wave epi scratch f32 16x68)
//   [33792, 43008):   aw 64 x 72 u16
//   [43008, 44032):   parts 64 rows x 2 lp x {mx, ps} f32
// 4 barriers per block. 2 blocks/CU (88 KB LDS, <=128 regs).
// ---------------------------------------------------------------------------
__global__ __launch_bounds__(512, 4) void main_kernel(
    const float* __restrict__ x, const u16* __restrict__ Wdf,
    const u16* __restrict__ mtf, const u16* __restrict__ t3f,
    const float* __restrict__ bd, float* __restrict__ out) {
  __shared__ __attribute__((aligned(16))) char smem[44032];
  u16* xs = (u16*)smem;                      // 64 x 264
  u16* aw = (u16*)(smem + 33792);            // 64 x 72
  float* parts = (float*)(smem + 43008);     // 64 x 2 x {mx, ps}

  const int bid = blockIdx.x;
  const int n  = bid / 49;
  const int pt = bid - n*49;
  const int m0 = pt * 64;
  const int tid = threadIdx.x, w = tid >> 6, lane = tid & 63;
  const int quad = lane >> 4, l16 = lane & 15;
  const int rg = w & 3;        // GEMM2 row-group (rows rg*16..rg*16+15)
  const int lp = w >> 2;       // GEMM2 l-pair (l-groups lp*2, lp*2+1)

  float bias[4];
  #pragma unroll
  for (int ot = 0; ot < 4; ++ot) bias[ot] = bd[w*64 + ot*16 + l16];

  // ---- stage x tile: 64x256 fp32 -> f16 LDS (coalesced float4) ----
  {
    const float4* xg = (const float4*)(x + (size_t)(n*3136 + m0)*256);
    #pragma unroll
    for (int it = 0; it < 8; ++it) {
      int idx = it*512 + tid;
      int r = idx >> 6, c4 = idx & 63;
      float4 v = xg[idx];
      ushort4 u;
      u.x = f2h(v.x); u.y = f2h(v.y); u.z = f2h(v.z); u.w = f2h(v.w);
      *(ushort4*)(&xs[r*264 + c4*4]) = u;
    }
  }
  __syncthreads();                                             // B1

  // ---- GEMM2: a[p,l] = xs @ Mt^T  (each wave: 16 rows x 32 l, K=256) ----
  f32x4 acc2[2];
  acc2[0] = (f32x4){0.f, 0.f, 0.f, 0.f};
  acc2[1] = (f32x4){0.f, 0.f, 0.f, 0.f};
  #pragma unroll
  for (int kc = 0; kc < 8; ++kc) {
    half8 a = *(const half8*)(&xs[(rg*16 + l16)*264 + kc*32 + quad*8]);
    #pragma unroll
    for (int j = 0; j < 2; ++j) {
      half8 bf = *(const half8*)(mtf + ((size_t)(n*4 + lp*2 + j)*8 + kc)*512 + lane*8);
      acc2[j] = mfma16(a, bf, acc2[j]);
    }
  }

  // ---- softmax partials over this wave's 32 l-cols ----
  float mx_[4], ps_[4], e0_[4], e1_[4];
  #pragma unroll
  for (int r = 0; r < 4; ++r) {
    float s0 = acc2[0][r], s1 = acc2[1][r];
    float mx = fmaxf(s0, s1);
    #pragma unroll
    for (int off = 8; off >= 1; off >>= 1) mx = fmaxf(mx, __shfl_xor(mx, off, 64));
    float e0 = __expf(s0 - mx), e1 = __expf(s1 - mx);
    float ps = e0 + e1;
    #pragma unroll
    for (int off = 8; off >= 1; off >>= 1) ps += __shfl_xor(ps, off, 64);
    mx_[r] = mx; ps_[r] = ps; e0_[r] = e0; e1_[r] = e1;
    if (l16 == 0) {
      int row = rg*16 + quad*4 + r;
      parts[(row*2 + lp)*2]     = mx;
      parts[(row*2 + lp)*2 + 1] = ps;
    }
  }
  __syncthreads();                                             // B2

  // ---- combine partials (online-softmax merge), write aw ----
  #pragma unroll
  for (int r = 0; r < 4; ++r) {
    int row = rg*16 + quad*4 + r;
    float mxo = parts[(row*2 + (1 - lp))*2];
    float pso = parts[(row*2 + (1 - lp))*2 + 1];
    float g  = fmaxf(mx_[r], mxo);
    float sA = __expf(mx_[r] - g), sB = __expf(mxo - g);
    float inv = 1.0f / (ps_[r]*sA + pso*sB);
    float scl = sA * inv;
    aw[row*72 + (lp*2)*16 + l16]     = f2h(e0_[r]*scl);
    aw[row*72 + (lp*2 + 1)*16 + l16] = f2h(e1_[r]*scl);
  }
  __syncthreads();                                             // B3

  // ---- GEMM4 (xs@Wd^T) + GEMM3 (aw@t3) into shared accumulator ----
  f32x4 acc[4][4];
  #pragma unroll
  for (int mt = 0; mt < 4; ++mt)
    #pragma unroll
    for (int ot = 0; ot < 4; ++ot) acc[mt][ot] = (f32x4){0.f, 0.f, 0.f, 0.f};
  #pragma unroll
  for (int kc = 0; kc < 8; ++kc) {
    half8 a[4];
    #pragma unroll
    for (int mt = 0; mt < 4; ++mt)
      a[mt] = *(const half8*)(&xs[(mt*16 + l16)*264 + kc*32 + quad*8]);
    #pragma unroll
    for (int ot = 0; ot < 4; ++ot) {
      half8 bf = *(const half8*)(Wdf + ((size_t)(w*4 + ot)*8 + kc)*512 + lane*8);
      #pragma unroll
      for (int mt = 0; mt < 4; ++mt) acc[mt][ot] = mfma16(a[mt], bf, acc[mt][ot]);
    }
  }
  #pragma unroll
  for (int kc3 = 0; kc3 < 2; ++kc3) {
    half8 a[4];
    #pragma unroll
    for (int mt = 0; mt < 4; ++mt)
      a[mt] = *(const half8*)(&aw[(mt*16 + l16)*72 + kc3*32 + quad*8]);
    #pragma unroll
    for (int ot = 0; ot < 4; ++ot) {
      half8 bf = *(const half8*)(t3f + ((size_t)(n*32 + w*4 + ot)*2 + kc3)*512 + lane*8);
      #pragma unroll
      for (int mt = 0; mt < 4; ++mt) acc[mt][ot] = mfma16(a[mt], bf, acc[mt][ot]);
    }
  }
  __syncthreads();   // B4: all xs + aw reads done -> scratch may alias

  // ---- epilogue: per-wave transpose in wave-private scratch (over dead xs);
  //      only wave-local lgkmcnt ordering needed, no further barriers. ----
  float* sc = (float*)smem + w*1088;   // 16 x 68 f32 = 4352 B per wave
  #pragma unroll
  for (int mt = 0; mt < 4; ++mt) {
    #pragma unroll
    for (int ot = 0; ot < 4; ++ot)
      #pragma unroll
      for (int r = 0; r < 4; ++r)
        sc[(quad*4 + r)*68 + ot*16 + l16] = acc[mt][ot][r] + bias[ot];
    #pragma unroll
    for (int i = 0; i < 4; ++i) {
      float4 v = *(float4*)&sc[(i*4 + quad)*68 + l16*4];
      *(float4*)&out[(size_t)(n*3136 + m0 + mt*16 + i*4 + quad)*512 + w*64 + l16*4] = v;
    }
  }
}

// ---------------------------------------------------------------------------
extern "C" void kernel_launch(void* const* d_in, const int* in_sizes, int n_in,
                              void* d_out, int out_size, void* d_ws, size_t ws_size,
                              hipStream_t stream) {
  const float* x  = (const float*)d_in[0];
  const float* t  = (const float*)d_in[1];
  const float* W1 = (const float*)d_in[2];
  const float* W2 = (const float*)d_in[3];
  const float* W3 = (const float*)d_in[4];
  const float* b3 = (const float*)d_in[5];
  const float* Wd = (const float*)d_in[6];
  const float* bd = (const float*)d_in[7];
  float* out = (float*)d_out;

  // workspace layout (bytes), ~2.75 MB total — all fragment-linear f16
  char* ws = (char*)d_ws;
  u16* W3f = (u16*)(ws + 0);        //  262144
  u16* Wdf = (u16*)(ws + 262144);   //  262144
  u16* tf  = (u16*)(ws + 524288);   //  524288
  u16* Gtf = (u16*)(ws + 1048576);  //  131072
  u16* mtf = (u16*)(ws + 1179648);  //  524288
  u16* t3f = (u16*)(ws + 1703936);  //  1048576  (end 2752512)

  hipLaunchKernelGGL(prep_kernel, dim3(2304), dim3(256), 0, stream,
                     W1, W2, W3, Wd, t, W3f, Wdf, tf, Gtf);
  hipLaunchKernelGGL(mt_t3_kernel, dim3(192), dim3(256), 0, stream,
                     tf, Gtf, W3f, b3, mtf, t3f);
  hipLaunchKernelGGL(main_kernel, dim3(784), dim3(512), 0, stream,
                     x, Wdf, mtf, t3f, bd, out);
}